// Round 8
// baseline (92.597 us; speedup 1.0000x reference)
//
#include <hip/hip_runtime.h>
#include <stdint.h>

// Problem constants (N=2, S=2048, E=1024, H=16, D=64)
#define S_LEN 2048
#define EMB 1024
#define NHEADS 16
#define HD 64
#define LOG2E 1.4426950408889634f
#define NROWS 65536  // N * H * S

typedef __bf16 bf16x8 __attribute__((ext_vector_type(8)));
typedef float f32x4 __attribute__((ext_vector_type(4)));
typedef unsigned short u16;

#define MFMA16(a, b, c) __builtin_amdgcn_mfma_f32_16x16x32_bf16(a, b, c, 0, 0, 0)
#define GLOAD_LDS16(gp, lp)                                        \
  __builtin_amdgcn_global_load_lds(                                \
      (const __attribute__((address_space(1))) unsigned int*)(gp), \
      (__attribute__((address_space(3))) unsigned int*)(lp), 16, 0, 0)

__device__ __forceinline__ u16 bf16r(float x) {
  union { float f; unsigned int u; } c; c.f = x;
  unsigned int u = c.u + 0x7fffu + ((c.u >> 16) & 1u);
  return (u16)(u >> 16);
}

__device__ __forceinline__ unsigned int cvt_pk_bf16(float lo, float hi) {
  unsigned int r;
  asm("v_cvt_pk_bf16_f32 %0, %1, %2" : "=v"(r) : "v"(lo), "v"(hi));
  return r;
}

__device__ __forceinline__ float fexp2(float x) {
  float r;
  asm("v_exp_f32 %0, %1" : "=v"(r) : "v"(x));
  return r;
}

// k-axis permutation applied to V columns so the PV A-fragment (P) is formed
// from each lane's own QK^T outputs with zero cross-lane traffic (16x16 MFMA).
__device__ __forceinline__ int kperm(int k) {
  int kb = (k >> 4) & 3, g = (k >> 2) & 3, r = k & 3;
  return (kb >> 1) * 32 + g * 8 + (kb & 1) * 4 + r;
}

// ---- fused preprocessing: V-transpose(+k-perm) | K cvt | W cvt | mask flags ----
__global__ __launch_bounds__(256) void prep_kernel(
    const float* __restrict__ values, const float* __restrict__ keys,
    const float* __restrict__ W, const int* __restrict__ mask,
    u16* __restrict__ vt, u16* __restrict__ kb, u16* __restrict__ wb,
    unsigned char* __restrict__ fl2) {
  __shared__ u16 tile[64][65];
  __shared__ int s_ok[4];
  int b = blockIdx.x;
  int t = threadIdx.x;
  if (b < 1024) {
    // V transpose: v[n][s][h*64+d] fp32 -> vt[n][h][d][kperm(s)] bf16
    int st = b & 31, h = (b >> 5) & 15, n = b >> 9;
    int s0 = st * 64;
    int d = t & 63, r4 = t >> 6;
#pragma unroll
    for (int i = 0; i < 16; ++i) {
      int s = r4 + i * 4;
      float x = values[(size_t)(n * S_LEN + s0 + s) * EMB + h * HD + d];
      tile[s][d] = bf16r(x);
    }
    __syncthreads();
    int sp = s0 + kperm(d);  // permuted column position
#pragma unroll
    for (int i = 0; i < 16; ++i) {
      int dd = r4 + i * 4;
      vt[(size_t)((n * NHEADS + h) * HD + dd) * S_LEN + sp] = tile[d][dd];
    }
  } else if (b < 2048) {
    // K fp32 -> bf16 (1,048,576 float4)
    int idx = (b - 1024) * 256 + t;
    const float4* in4 = (const float4*)keys;
    ushort4* out4 = (ushort4*)kb;
#pragma unroll
    for (int j = 0; j < 4; ++j) {
      float4 v = in4[idx + j * 262144];
      ushort4 o;
      o.x = bf16r(v.x); o.y = bf16r(v.y); o.z = bf16r(v.z); o.w = bf16r(v.w);
      out4[idx + j * 262144] = o;
    }
  } else if (b < 2304) {
    // W fp32 -> bf16 (262,144 float4)
    int idx = (b - 2048) * 256 + t;
    const float4* in4 = (const float4*)W;
    ushort4* out4 = (ushort4*)wb;
#pragma unroll
    for (int j = 0; j < 4; ++j) {
      float4 v = in4[idx + j * 65536];
      ushort4 o;
      o.x = bf16r(v.x); o.y = bf16r(v.y); o.z = bf16r(v.z); o.w = bf16r(v.w);
      out4[idx + j * 65536] = o;
    }
  } else {
    // mask flags: fl2[(n*16+qt)*32+kt] = all(mask block 128q x 64k != 0)
    int idx = b - 2304;
    int kt = idx & 31, qt = (idx >> 5) & 15, n = idx >> 9;
    int qr = t >> 1, c8 = t & 1;
    const int4* mp = (const int4*)(mask + (size_t)n * S_LEN * S_LEN +
                                   (size_t)(qt * 128 + qr) * S_LEN + kt * 64) + c8 * 8;
    int ok = 1;
#pragma unroll
    for (int i = 0; i < 8; ++i) {
      int4 m = mp[i];
      ok &= (m.x != 0) & (m.y != 0) & (m.z != 0) & (m.w != 0);
    }
    ok = __all(ok);
    if ((t & 63) == 0) s_ok[t >> 6] = ok;
    __syncthreads();
    if (t == 0) fl2[idx] = (unsigned char)(s_ok[0] & s_ok[1] & s_ok[2] & s_ok[3]);
  }
}

// ---- flash attention, split-K by 2: each block does 16 of 32 K/V tiles ----
// 4 waves x 32 q (2x16 subtiles) = 128 q/block, grid 1024 (4 blocks/CU).
// Swapped QK^T, log2-domain softmax, defer-max, in-register P (k-permuted V),
// prefetch dbuf staging. Writes unnormalized fp32 partials + (m,l) per row.
__global__ __launch_bounds__(256, 4) void attn_kernel(
    const float* __restrict__ query, const u16* __restrict__ kbuf,
    const u16* __restrict__ vt, const int* __restrict__ mask,
    const unsigned char* __restrict__ fl2, float* __restrict__ po,
    float2* __restrict__ ml) {
  __shared__ __align__(16) unsigned char kl[2][8192];  // K tile [64 k][64 d] dbuf, swizzled
  __shared__ __align__(16) unsigned char vl[2][8192];  // Vt tile [64 d][64 k'] dbuf, swizzled

  int b = blockIdx.x;
  b = (b & 7) * 128 + (b >> 3);  // XCD swizzle: 4 heads (both halves) per XCD
  int qt = b & 15, half = (b >> 4) & 1, h = (b >> 5) & 15, n = b >> 9;
  int t = threadIdx.x, w = t >> 6, l = t & 63, l16 = l & 15, g = l >> 4;
  int q0 = qt * 128 + w * 32;  // wave q base; subtile u covers q0+u*16 .. +15
  int kt0 = half * 16;

  // Q fragments (B-operand of swapped QK): pre-scale by LOG2E/32 -> log2 domain
  const float QS = 0.03125f * LOG2E;
  bf16x8 aq[2][2];
#pragma unroll
  for (int u = 0; u < 2; ++u)
#pragma unroll
    for (int hh = 0; hh < 2; ++hh) {
      const float* qp = query + (size_t)(n * S_LEN + q0 + u * 16 + l16) * EMB +
                        h * HD + hh * 32 + g * 8;
      float4 f0 = *(const float4*)qp;
      float4 f1 = *(const float4*)(qp + 4);
      union { bf16x8 v; unsigned int u32[4]; } qq;
      qq.u32[0] = cvt_pk_bf16(f0.x * QS, f0.y * QS);
      qq.u32[1] = cvt_pk_bf16(f0.z * QS, f0.w * QS);
      qq.u32[2] = cvt_pk_bf16(f1.x * QS, f1.y * QS);
      qq.u32[3] = cvt_pk_bf16(f1.z * QS, f1.w * QS);
      aq[u][hh] = qq.v;
    }

  f32x4 zero4 = {0.f, 0.f, 0.f, 0.f};
  f32x4 acc[2][4];
  float lrun[2] = {0.f, 0.f}, mrun[2] = {0.f, 0.f};
#pragma unroll
  for (int u = 0; u < 2; ++u)
#pragma unroll
    for (int db = 0; db < 4; ++db) acc[u][db] = zero4;

  int row_s = t >> 3, cc = t & 7;  // staging row 0..31, 16B chunk 0..7
  int sc = cc ^ (row_s & 7);       // pre-swizzled source chunk
  const u16* gk0 = kbuf + (size_t)(n * S_LEN + row_s) * EMB + h * HD + sc * 8;
  const u16* gv0 = vt + (size_t)((n * NHEADS + h) * HD + row_s) * S_LEN + sc * 8;

  auto stage = [&](int kt, int nb) {
    const u16* gk = gk0 + (size_t)kt * 64 * EMB;
    const u16* gv = gv0 + kt * 64;
    GLOAD_LDS16(gk, kl[nb] + (w * 64) * 16);
    GLOAD_LDS16(gk + 32 * EMB, kl[nb] + (256 + w * 64) * 16);
    GLOAD_LDS16(gv, vl[nb] + (w * 64) * 16);
    GLOAD_LDS16(gv + 32 * S_LEN, vl[nb] + (256 + w * 64) * 16);
  };

  stage(kt0, 0);
  __syncthreads();  // first tile staged

  for (int kt = kt0; kt < kt0 + 16; ++kt) {
    int cur = kt & 1;
    if (kt + 1 < kt0 + 16) stage(kt + 1, cur ^ 1);  // prefetch next tile
    const unsigned char* kc = kl[cur];
    const unsigned char* vc = vl[cur];

    // S^T = K Q^T : lane (l16,g) -> S[k=kb*16+g*4+r][q=q0+u*16+l16] (log2 units)
    f32x4 sf[2][4];
    __builtin_amdgcn_s_setprio(1);
#pragma unroll
    for (int kb = 0; kb < 4; ++kb) {
      int row = kb * 16 + l16;
      const unsigned char* kr = kc + row * 128;
      int sw = (row & 7) << 4;
      bf16x8 bk0 = *(const bf16x8*)(kr + ((g * 16) ^ sw));
      bf16x8 bk1 = *(const bf16x8*)(kr + ((64 + g * 16) ^ sw));
#pragma unroll
      for (int u = 0; u < 2; ++u) {
        f32x4 z = zero4;
        z = MFMA16(bk0, aq[u][0], z);
        z = MFMA16(bk1, aq[u][1], z);
        sf[u][kb] = z;
      }
    }
    __builtin_amdgcn_s_setprio(0);

    unsigned char fflag = fl2[((n * 16 + qt) * 32) + kt];
    if (!fflag) {  // rare: per-element mask (log2 domain: -100 ~ zero prob)
#pragma unroll
      for (int u = 0; u < 2; ++u) {
        const int* mrow = mask + (size_t)n * S_LEN * S_LEN +
                          (size_t)(q0 + u * 16 + l16) * S_LEN + kt * 64 + g * 4;
#pragma unroll
        for (int kb = 0; kb < 4; ++kb) {
          int4 mm = *(const int4*)(mrow + kb * 16);
          if (mm.x == 0) sf[u][kb][0] = -100.f;
          if (mm.y == 0) sf[u][kb][1] = -100.f;
          if (mm.z == 0) sf[u][kb][2] = -100.f;
          if (mm.w == 0) sf[u][kb][3] = -100.f;
        }
      }
    }

    bf16x8 pa[2][2];
#pragma unroll
    for (int u = 0; u < 2; ++u) {
      // defer-max: in-register max over this lane's 16 values (one q-row)
      float lmax = sf[u][0][0];
#pragma unroll
      for (int kb = 0; kb < 4; ++kb)
#pragma unroll
        for (int r = 0; r < 4; ++r) lmax = fmaxf(lmax, sf[u][kb][r]);
      if (!__all(lmax <= mrun[u] + 8.f)) {  // rare rescale path
        float rmax = fmaxf(lmax, __shfl_xor(lmax, 16));
        rmax = fmaxf(rmax, __shfl_xor(rmax, 32));
        float Mn = fmaxf(mrun[u], rmax);
        float corr = fexp2(mrun[u] - Mn);
        mrun[u] = Mn;
        lrun[u] *= corr;
#pragma unroll
        for (int r = 0; r < 4; ++r) {
          float ca = __shfl(corr, (l & 48) + (g << 2) + r);
#pragma unroll
          for (int db = 0; db < 4; ++db) acc[u][db][r] *= ca;
        }
      }
      // p = 2^(s - m), lane-partial sum, pack A-fragments in-register (k-perm)
      float p[4][4];
#pragma unroll
      for (int kb = 0; kb < 4; ++kb)
#pragma unroll
        for (int r = 0; r < 4; ++r)
          p[kb][r] = fexp2(sf[u][kb][r] - mrun[u]);
      float s01 = (p[0][0] + p[0][1]) + (p[0][2] + p[0][3]);
      float s23 = (p[1][0] + p[1][1]) + (p[1][2] + p[1][3]);
      float s45 = (p[2][0] + p[2][1]) + (p[2][2] + p[2][3]);
      float s67 = (p[3][0] + p[3][1]) + (p[3][2] + p[3][3]);
      lrun[u] += (s01 + s23) + (s45 + s67);
#pragma unroll
      for (int hh = 0; hh < 2; ++hh) {
        union { bf16x8 v; unsigned int u32[4]; } pp;
        pp.u32[0] = cvt_pk_bf16(p[2 * hh][0], p[2 * hh][1]);
        pp.u32[1] = cvt_pk_bf16(p[2 * hh][2], p[2 * hh][3]);
        pp.u32[2] = cvt_pk_bf16(p[2 * hh + 1][0], p[2 * hh + 1][1]);
        pp.u32[3] = cvt_pk_bf16(p[2 * hh + 1][2], p[2 * hh + 1][3]);
        pa[u][hh] = pp.v;
      }
    }

    // O += P V : A = in-register P, B = permuted Vt rows shared across subtiles
    __builtin_amdgcn_s_setprio(1);
#pragma unroll
    for (int hh = 0; hh < 2; ++hh)
#pragma unroll
      for (int db = 0; db < 4; ++db) {
        int d = db * 16 + l16;
        bf16x8 bv = *(const bf16x8*)(vc + d * 128 + ((hh * 64 + g * 16) ^ ((d & 7) << 4)));
        acc[0][db] = MFMA16(pa[0][hh], bv, acc[0][db]);
        acc[1][db] = MFMA16(pa[1][hh], bv, acc[1][db]);
      }
    __builtin_amdgcn_s_setprio(0);

    __syncthreads();  // all waves done reading cur; prefetch landed
  }

  // epilogue: write unnormalized fp32 partials + per-row (m, l)
  size_t rowbase = (size_t)(n * NHEADS + h) * S_LEN + q0;
#pragma unroll
  for (int u = 0; u < 2; ++u) {
    float s = lrun[u];
    s += __shfl_xor(s, 16);
    s += __shfl_xor(s, 32);  // full row sum for row l16 (this half)
    if (g == 0) {
      float2 v; v.x = mrun[u]; v.y = s;
      ml[(size_t)half * NROWS + rowbase + u * 16 + l16] = v;
    }
#pragma unroll
    for (int db = 0; db < 4; ++db)
#pragma unroll
      for (int r = 0; r < 4; ++r) {
        size_t rq = rowbase + u * 16 + (g << 2) + r;
        po[((size_t)half * NROWS + rq) * HD + db * 16 + l16] = acc[u][db][r];
      }
  }
}

// ---- combine: merge two split-K halves with online-softmax algebra ----
__global__ __launch_bounds__(256) void combine_kernel(
    const float* __restrict__ po, const float2* __restrict__ ml,
    u16* __restrict__ ob) {
  int idx = blockIdx.x * 256 + threadIdx.x;
  int stride = gridDim.x * 256;
  for (; idx < NROWS * 16; idx += stride) {  // float4 units (4 d each)
    int row = idx >> 4, d4 = idx & 15;
    float2 a = ml[row], b = ml[NROWS + row];
    float m = fmaxf(a.x, b.x);
    float c0 = fexp2(a.x - m), c1 = fexp2(b.x - m);
    float rinv = 1.f / (a.y * c0 + b.y * c1);
    c0 *= rinv; c1 *= rinv;
    float4 o0 = ((const float4*)po)[(size_t)row * 16 + d4];
    float4 o1 = ((const float4*)po)[(size_t)NROWS * 16 + (size_t)row * 16 + d4];
    ushort4 o;
    o.x = bf16r(o0.x * c0 + o1.x * c1);
    o.y = bf16r(o0.y * c0 + o1.y * c1);
    o.z = bf16r(o0.z * c0 + o1.z * c1);
    o.w = bf16r(o0.w * c0 + o1.w * c1);
    int n = row >> 15, h = (row >> 11) & 15, q = row & 2047;
    *(ushort4*)(ob + (size_t)(n * S_LEN + q) * EMB + h * HD + d4 * 4) = o;
  }
}

// ---- output projection: C[4096][1024] = O_bf16 @ W_bf16^T + bias ----
// 128x64 tile, grid (32,16) = 512 blocks (2/CU), prefetch dbuf staging.
__global__ __launch_bounds__(256) void proj_kernel(
    const u16* __restrict__ A, const u16* __restrict__ Bt,
    const float* __restrict__ bias, float* __restrict__ C) {
  __shared__ __align__(16) unsigned char al[2][16384];
  __shared__ __align__(16) unsigned char bl[2][8192];
  int bm = blockIdx.x, bn = blockIdx.y;
  int t = threadIdx.x, w = t >> 6, l = t & 63;
  int l16 = l & 15, g = l >> 4;
  f32x4 zero4 = {0.f, 0.f, 0.f, 0.f};
  f32x4 acc[2][4];
#pragma unroll
  for (int mi = 0; mi < 2; ++mi)
#pragma unroll
    for (int nj = 0; nj < 4; ++nj) acc[mi][nj] = zero4;
  int row_s = t >> 3, cc = t & 7;
  int sc = cc ^ (row_s & 7);
  const u16* ga0 = A + (size_t)(bm * 128 + row_s) * EMB + sc * 8;
  const u16* gb0 = Bt + (size_t)(bn * 64 + row_s) * EMB + sc * 8;

  auto stage = [&](int ks, int nb) {
#pragma unroll
    for (int i = 0; i < 4; ++i)
      GLOAD_LDS16(ga0 + (size_t)i * 32 * EMB + ks * 64, al[nb] + (i * 256 + w * 64) * 16);
#pragma unroll
    for (int i = 0; i < 2; ++i)
      GLOAD_LDS16(gb0 + (size_t)i * 32 * EMB + ks * 64, bl[nb] + (i * 256 + w * 64) * 16);
  };

  stage(0, 0);
  __syncthreads();

  for (int ks = 0; ks < 16; ++ks) {
    int cur = ks & 1;
    if (ks + 1 < 16) stage(ks + 1, cur ^ 1);
    __builtin_amdgcn_s_setprio(1);
#pragma unroll
    for (int hh = 0; hh < 2; ++hh) {
      bf16x8 af[2], bfr[4];
#pragma unroll
      for (int mi = 0; mi < 2; ++mi) {
        int row = w * 32 + mi * 16 + l16;
        af[mi] = *(const bf16x8*)(al[cur] + row * 128 + ((hh * 64 + g * 16) ^ ((row & 7) << 4)));
      }
#pragma unroll
      for (int nj = 0; nj < 4; ++nj) {
        int row = nj * 16 + l16;
        bfr[nj] = *(const bf16x8*)(bl[cur] + row * 128 + ((hh * 64 + g * 16) ^ ((row & 7) << 4)));
      }
#pragma unroll
      for (int mi = 0; mi < 2; ++mi)
#pragma unroll
        for (int nj = 0; nj < 4; ++nj) acc[mi][nj] = MFMA16(af[mi], bfr[nj], acc[mi][nj]);
    }
    __builtin_amdgcn_s_setprio(0);
    __syncthreads();
  }
#pragma unroll
  for (int nj = 0; nj < 4; ++nj) {
    int j = bn * 64 + nj * 16 + l16;
    float bj = bias[j];
#pragma unroll
    for (int mi = 0; mi < 2; ++mi) {
      int i0 = bm * 128 + w * 32 + mi * 16 + g * 4;
#pragma unroll
      for (int r = 0; r < 4; ++r) C[(size_t)(i0 + r) * EMB + j] = acc[mi][nj][r] + bj;
    }
  }
}

extern "C" void kernel_launch(void* const* d_in, const int* in_sizes, int n_in,
                              void* d_out, int out_size, void* d_ws, size_t ws_size,
                              hipStream_t stream) {
  const float* values = (const float*)d_in[0];
  const float* keys = (const float*)d_in[1];
  const float* query = (const float*)d_in[2];
  const int* mask = (const int*)d_in[3];
  const float* W = (const float*)d_in[4];
  const float* bias = (const float*)d_in[5];
  float* out = (float*)d_out;

  u16* kb = (u16*)d_ws;                    // 8 MB
  u16* vt = kb + 4194304;                  // 8 MB
  u16* ob = vt + 4194304;                  // 8 MB
  u16* wb = ob + 4194304;                  // 2 MB
  unsigned char* fl2 = (unsigned char*)(wb + 1048576);  // 64 KB reserved
  float* po = (float*)(fl2 + 65536);       // 2 * 65536 * 64 fp32 = 32 MB
  float2* ml = (float2*)(po + 2 * (size_t)NROWS * HD);  // 1 MB

  prep_kernel<<<3328, 256, 0, stream>>>(values, keys, W, mask, vt, kb, wb, fl2);
  attn_kernel<<<1024, 256, 0, stream>>>(query, kb, vt, mask, fl2, po, ml);
  combine_kernel<<<2048, 256, 0, stream>>>(po, ml, ob);
  proj_kernel<<<dim3(32, 16), 256, 0, stream>>>(ob, wb, bias, out);
}

// Round 9
// 90.895 us; speedup vs baseline: 1.0187x; 1.0187x over previous
//
#include <hip/hip_runtime.h>
#include <stdint.h>

// Problem constants (N=2, S=2048, E=1024, H=16, D=64)
#define S_LEN 2048
#define EMB 1024
#define NHEADS 16
#define HD 64
#define LOG2E 1.4426950408889634f
#define NROWS 65536  // N * H * S

typedef __bf16 bf16x8 __attribute__((ext_vector_type(8)));
typedef float f32x4 __attribute__((ext_vector_type(4)));
typedef unsigned short u16;

#define MFMA16(a, b, c) __builtin_amdgcn_mfma_f32_16x16x32_bf16(a, b, c, 0, 0, 0)
#define GLOAD_LDS16(gp, lp)                                        \
  __builtin_amdgcn_global_load_lds(                                \
      (const __attribute__((address_space(1))) unsigned int*)(gp), \
      (__attribute__((address_space(3))) unsigned int*)(lp), 16, 0, 0)

__device__ __forceinline__ u16 bf16r(float x) {
  union { float f; unsigned int u; } c; c.f = x;
  unsigned int u = c.u + 0x7fffu + ((c.u >> 16) & 1u);
  return (u16)(u >> 16);
}

__device__ __forceinline__ unsigned int cvt_pk_bf16(float lo, float hi) {
  unsigned int r;
  asm("v_cvt_pk_bf16_f32 %0, %1, %2" : "=v"(r) : "v"(lo), "v"(hi));
  return r;
}

__device__ __forceinline__ float fexp2(float x) {
  float r;
  asm("v_exp_f32 %0, %1" : "=v"(r) : "v"(x));
  return r;
}

__device__ __forceinline__ float fmax3(float a, float b, float c) {
  float r;
  asm("v_max3_f32 %0, %1, %2, %3" : "=v"(r) : "v"(a), "v"(b), "v"(c));
  return r;
}

// k-axis permutation applied to V columns so the PV A-fragment (P) is formed
// from each lane's own QK^T outputs with zero cross-lane traffic (16x16 MFMA).
__device__ __forceinline__ int kperm(int k) {
  int kb = (k >> 4) & 3, g = (k >> 2) & 3, r = k & 3;
  return (kb >> 1) * 32 + g * 8 + (kb & 1) * 4 + r;
}

// ---- fused preprocessing: V-transpose(+k-perm) | K cvt | W cvt | mask flags ----
__global__ __launch_bounds__(256) void prep_kernel(
    const float* __restrict__ values, const float* __restrict__ keys,
    const float* __restrict__ W, const int* __restrict__ mask,
    u16* __restrict__ vt, u16* __restrict__ kb, u16* __restrict__ wb,
    unsigned char* __restrict__ fl2) {
  __shared__ u16 tile[64][65];
  __shared__ int s_ok[4];
  int b = blockIdx.x;
  int t = threadIdx.x;
  if (b < 1024) {
    // V transpose: v[n][s][h*64+d] fp32 -> vt[n][h][d][kperm(s)] bf16
    int st = b & 31, h = (b >> 5) & 15, n = b >> 9;
    int s0 = st * 64;
    int d = t & 63, r4 = t >> 6;
#pragma unroll
    for (int i = 0; i < 16; ++i) {
      int s = r4 + i * 4;
      float x = values[(size_t)(n * S_LEN + s0 + s) * EMB + h * HD + d];
      tile[s][d] = bf16r(x);
    }
    __syncthreads();
    int sp = s0 + kperm(d);  // permuted column position
#pragma unroll
    for (int i = 0; i < 16; ++i) {
      int dd = r4 + i * 4;
      vt[(size_t)((n * NHEADS + h) * HD + dd) * S_LEN + sp] = tile[d][dd];
    }
  } else if (b < 2048) {
    // K fp32 -> bf16 (1,048,576 float4)
    int idx = (b - 1024) * 256 + t;
    const float4* in4 = (const float4*)keys;
    ushort4* out4 = (ushort4*)kb;
#pragma unroll
    for (int j = 0; j < 4; ++j) {
      float4 v = in4[idx + j * 262144];
      ushort4 o;
      o.x = bf16r(v.x); o.y = bf16r(v.y); o.z = bf16r(v.z); o.w = bf16r(v.w);
      out4[idx + j * 262144] = o;
    }
  } else if (b < 2304) {
    // W fp32 -> bf16 (262,144 float4)
    int idx = (b - 2048) * 256 + t;
    const float4* in4 = (const float4*)W;
    ushort4* out4 = (ushort4*)wb;
#pragma unroll
    for (int j = 0; j < 4; ++j) {
      float4 v = in4[idx + j * 65536];
      ushort4 o;
      o.x = bf16r(v.x); o.y = bf16r(v.y); o.z = bf16r(v.z); o.w = bf16r(v.w);
      out4[idx + j * 65536] = o;
    }
  } else {
    // mask flags: fl2[(n*16+qt)*32+kt] = all(mask block 128q x 64k != 0)
    int idx = b - 2304;
    int kt = idx & 31, qt = (idx >> 5) & 15, n = idx >> 9;
    int qr = t >> 1, c8 = t & 1;
    const int4* mp = (const int4*)(mask + (size_t)n * S_LEN * S_LEN +
                                   (size_t)(qt * 128 + qr) * S_LEN + kt * 64) + c8 * 8;
    int ok = 1;
#pragma unroll
    for (int i = 0; i < 8; ++i) {
      int4 m = mp[i];
      ok &= (m.x != 0) & (m.y != 0) & (m.z != 0) & (m.w != 0);
    }
    ok = __all(ok);
    if ((t & 63) == 0) s_ok[t >> 6] = ok;
    __syncthreads();
    if (t == 0) fl2[idx] = (unsigned char)(s_ok[0] & s_ok[1] & s_ok[2] & s_ok[3]);
  }
}

// ---- flash attention, split-K by 2: each block does 16 of 32 K/V tiles ----
// 4 waves x 32 q (2x16 subtiles) = 128 q/block, grid 1024 (4 blocks/CU).
// Swapped QK^T, log2-domain softmax, defer-max (v_max3 tree), skip-sub fast
// path, row-sum via MFMA(P, ones), in-register P (k-permuted V), prefetch
// dbuf staging. Writes unnormalized fp32 partials + (m,l) per row.
__global__ __launch_bounds__(256, 4) void attn_kernel(
    const float* __restrict__ query, const u16* __restrict__ kbuf,
    const u16* __restrict__ vt, const int* __restrict__ mask,
    const unsigned char* __restrict__ fl2, float* __restrict__ po,
    float2* __restrict__ ml) {
  __shared__ __align__(16) unsigned char kl[2][8192];  // K tile [64 k][64 d] dbuf, swizzled
  __shared__ __align__(16) unsigned char vl[2][8192];  // Vt tile [64 d][64 k'] dbuf, swizzled

  int b = blockIdx.x;
  b = (b & 7) * 128 + (b >> 3);  // XCD swizzle: 4 heads (both halves) per XCD
  int qt = b & 15, half = (b >> 4) & 1, h = (b >> 5) & 15, n = b >> 9;
  int t = threadIdx.x, w = t >> 6, l = t & 63, l16 = l & 15, g = l >> 4;
  int q0 = qt * 128 + w * 32;  // wave q base; subtile u covers q0+u*16 .. +15
  int kt0 = half * 16;

  // Q fragments (B-operand of swapped QK): pre-scale by LOG2E/32 -> log2 domain
  const float QS = 0.03125f * LOG2E;
  bf16x8 aq[2][2];
#pragma unroll
  for (int u = 0; u < 2; ++u)
#pragma unroll
    for (int hh = 0; hh < 2; ++hh) {
      const float* qp = query + (size_t)(n * S_LEN + q0 + u * 16 + l16) * EMB +
                        h * HD + hh * 32 + g * 8;
      float4 f0 = *(const float4*)qp;
      float4 f1 = *(const float4*)(qp + 4);
      union { bf16x8 v; unsigned int u32[4]; } qq;
      qq.u32[0] = cvt_pk_bf16(f0.x * QS, f0.y * QS);
      qq.u32[1] = cvt_pk_bf16(f0.z * QS, f0.w * QS);
      qq.u32[2] = cvt_pk_bf16(f1.x * QS, f1.y * QS);
      qq.u32[3] = cvt_pk_bf16(f1.z * QS, f1.w * QS);
      aq[u][hh] = qq.v;
    }

  // all-ones bf16 B-fragment for the row-sum MFMA
  union { bf16x8 v; unsigned int u32[4]; } one_i;
  one_i.u32[0] = 0x3F803F80u; one_i.u32[1] = 0x3F803F80u;
  one_i.u32[2] = 0x3F803F80u; one_i.u32[3] = 0x3F803F80u;
  bf16x8 ones = one_i.v;

  f32x4 zero4 = {0.f, 0.f, 0.f, 0.f};
  f32x4 acc[2][4];
  float lrun[2] = {0.f, 0.f}, mrun[2] = {0.f, 0.f};
#pragma unroll
  for (int u = 0; u < 2; ++u)
#pragma unroll
    for (int db = 0; db < 4; ++db) acc[u][db] = zero4;

  int row_s = t >> 3, cc = t & 7;  // staging row 0..31, 16B chunk 0..7
  int sc = cc ^ (row_s & 7);       // pre-swizzled source chunk
  const u16* gk0 = kbuf + (size_t)(n * S_LEN + row_s) * EMB + h * HD + sc * 8;
  const u16* gv0 = vt + (size_t)((n * NHEADS + h) * HD + row_s) * S_LEN + sc * 8;

  auto stage = [&](int kt, int nb) {
    const u16* gk = gk0 + (size_t)kt * 64 * EMB;
    const u16* gv = gv0 + kt * 64;
    GLOAD_LDS16(gk, kl[nb] + (w * 64) * 16);
    GLOAD_LDS16(gk + 32 * EMB, kl[nb] + (256 + w * 64) * 16);
    GLOAD_LDS16(gv, vl[nb] + (w * 64) * 16);
    GLOAD_LDS16(gv + 32 * S_LEN, vl[nb] + (256 + w * 64) * 16);
  };

  stage(kt0, 0);
  __syncthreads();  // first tile staged

  for (int kt = kt0; kt < kt0 + 16; ++kt) {
    int cur = kt & 1;
    if (kt + 1 < kt0 + 16) stage(kt + 1, cur ^ 1);  // prefetch next tile
    const unsigned char* kc = kl[cur];
    const unsigned char* vc = vl[cur];

    // S^T = K Q^T : lane (l16,g) -> S[k=kb*16+g*4+r][q=q0+u*16+l16] (log2 units)
    f32x4 sf[2][4];
    __builtin_amdgcn_s_setprio(1);
#pragma unroll
    for (int kb = 0; kb < 4; ++kb) {
      int row = kb * 16 + l16;
      const unsigned char* kr = kc + row * 128;
      int sw = (row & 7) << 4;
      bf16x8 bk0 = *(const bf16x8*)(kr + ((g * 16) ^ sw));
      bf16x8 bk1 = *(const bf16x8*)(kr + ((64 + g * 16) ^ sw));
#pragma unroll
      for (int u = 0; u < 2; ++u) {
        f32x4 z = zero4;
        z = MFMA16(bk0, aq[u][0], z);
        z = MFMA16(bk1, aq[u][1], z);
        sf[u][kb] = z;
      }
    }
    __builtin_amdgcn_s_setprio(0);

    unsigned char fflag = fl2[((n * 16 + qt) * 32) + kt];
    if (!fflag) {  // rare: per-element mask (log2 domain: -100 ~ zero prob)
#pragma unroll
      for (int u = 0; u < 2; ++u) {
        const int* mrow = mask + (size_t)n * S_LEN * S_LEN +
                          (size_t)(q0 + u * 16 + l16) * S_LEN + kt * 64 + g * 4;
#pragma unroll
        for (int kb = 0; kb < 4; ++kb) {
          int4 mm = *(const int4*)(mrow + kb * 16);
          if (mm.x == 0) sf[u][kb][0] = -100.f;
          if (mm.y == 0) sf[u][kb][1] = -100.f;
          if (mm.z == 0) sf[u][kb][2] = -100.f;
          if (mm.w == 0) sf[u][kb][3] = -100.f;
        }
      }
    }

    bf16x8 pa[2][2];
#pragma unroll
    for (int u = 0; u < 2; ++u) {
      // defer-max: v_max3 tree over this lane's 16 values (its k-slice of row l16)
      float a0 = fmax3(sf[u][0][0], sf[u][0][1], sf[u][0][2]);
      float a1 = fmax3(sf[u][0][3], sf[u][1][0], sf[u][1][1]);
      float a2 = fmax3(sf[u][1][2], sf[u][1][3], sf[u][2][0]);
      float a3 = fmax3(sf[u][2][1], sf[u][2][2], sf[u][2][3]);
      float a4 = fmax3(sf[u][3][0], sf[u][3][1], sf[u][3][2]);
      float lmax = fmaxf(fmax3(a0, a1, a2), fmax3(a3, a4, sf[u][3][3]));
      if (!__all(lmax <= mrun[u] + 8.f)) {  // rare rescale path
        float rmax = fmaxf(lmax, __shfl_xor(lmax, 16));
        rmax = fmaxf(rmax, __shfl_xor(rmax, 32));
        float Mn = fmaxf(mrun[u], rmax);
        float corr = fexp2(mrun[u] - Mn);
        mrun[u] = Mn;
        lrun[u] *= corr;
#pragma unroll
        for (int r = 0; r < 4; ++r) {
          float ca = __shfl(corr, (l & 48) + (g << 2) + r);
#pragma unroll
          for (int db = 0; db < 4; ++db) acc[u][db][r] *= ca;
        }
      }
      // p = 2^(s - m); fast path skips the subtract while mrun == 0 (common)
      float p[4][4];
      if (__all(mrun[u] == 0.f)) {
#pragma unroll
        for (int kb = 0; kb < 4; ++kb)
#pragma unroll
          for (int r = 0; r < 4; ++r) p[kb][r] = fexp2(sf[u][kb][r]);
      } else {
#pragma unroll
        for (int kb = 0; kb < 4; ++kb)
#pragma unroll
          for (int r = 0; r < 4; ++r) p[kb][r] = fexp2(sf[u][kb][r] - mrun[u]);
      }
      // pack A-fragments in-register (k-perm layout)
#pragma unroll
      for (int hh = 0; hh < 2; ++hh) {
        union { bf16x8 v; unsigned int u32[4]; } pp;
        pp.u32[0] = cvt_pk_bf16(p[2 * hh][0], p[2 * hh][1]);
        pp.u32[1] = cvt_pk_bf16(p[2 * hh][2], p[2 * hh][3]);
        pp.u32[2] = cvt_pk_bf16(p[2 * hh + 1][0], p[2 * hh + 1][1]);
        pp.u32[3] = cvt_pk_bf16(p[2 * hh + 1][2], p[2 * hh + 1][3]);
        pa[u][hh] = pp.v;
      }
      // row sum via MFMA(P, ones): z[r] = full-tile rowsum(q-row g*4+r);
      // redistribute so this lane (owner of row l16) gets rowsum(l16).
      f32x4 z = zero4;
      z = MFMA16(pa[u][0], ones, z);
      z = MFMA16(pa[u][1], ones, z);
      float z01 = (l16 & 1) ? z[1] : z[0];
      float z23 = (l16 & 1) ? z[3] : z[2];
      float zsel = (l16 & 2) ? z23 : z01;
      lrun[u] += __shfl(zsel, ((l16 >> 2) << 4) + (l16 & 3));
    }

    // O += P V : A = in-register P, B = permuted Vt rows shared across subtiles
    __builtin_amdgcn_s_setprio(1);
#pragma unroll
    for (int hh = 0; hh < 2; ++hh)
#pragma unroll
      for (int db = 0; db < 4; ++db) {
        int d = db * 16 + l16;
        bf16x8 bv = *(const bf16x8*)(vc + d * 128 + ((hh * 64 + g * 16) ^ ((d & 7) << 4)));
        acc[0][db] = MFMA16(pa[0][hh], bv, acc[0][db]);
        acc[1][db] = MFMA16(pa[1][hh], bv, acc[1][db]);
      }
    __builtin_amdgcn_s_setprio(0);

    __syncthreads();  // all waves done reading cur; prefetch landed
  }

  // epilogue: lrun already holds full row sums; write fp32 partials + (m, l)
  size_t rowbase = (size_t)(n * NHEADS + h) * S_LEN + q0;
#pragma unroll
  for (int u = 0; u < 2; ++u) {
    if (g == 0) {
      float2 v; v.x = mrun[u]; v.y = lrun[u];
      ml[(size_t)half * NROWS + rowbase + u * 16 + l16] = v;
    }
#pragma unroll
    for (int db = 0; db < 4; ++db)
#pragma unroll
      for (int r = 0; r < 4; ++r) {
        size_t rq = rowbase + u * 16 + (g << 2) + r;
        po[((size_t)half * NROWS + rq) * HD + db * 16 + l16] = acc[u][db][r];
      }
  }
}

// ---- combine: merge two split-K halves with online-softmax algebra ----
// Exact-size grid: one float4-unit (4 d) per thread, no stride loop.
__global__ __launch_bounds__(256) void combine_kernel(
    const float* __restrict__ po, const float2* __restrict__ ml,
    u16* __restrict__ ob) {
  int idx = blockIdx.x * 256 + threadIdx.x;  // 0 .. NROWS*16-1
  int row = idx >> 4, d4 = idx & 15;
  float2 a = ml[row], b = ml[NROWS + row];
  float m = fmaxf(a.x, b.x);
  float c0 = fexp2(a.x - m), c1 = fexp2(b.x - m);
  float rinv = 1.f / (a.y * c0 + b.y * c1);
  c0 *= rinv; c1 *= rinv;
  float4 o0 = ((const float4*)po)[(size_t)row * 16 + d4];
  float4 o1 = ((const float4*)po)[(size_t)NROWS * 16 + (size_t)row * 16 + d4];
  ushort4 o;
  o.x = bf16r(o0.x * c0 + o1.x * c1);
  o.y = bf16r(o0.y * c0 + o1.y * c1);
  o.z = bf16r(o0.z * c0 + o1.z * c1);
  o.w = bf16r(o0.w * c0 + o1.w * c1);
  int n = row >> 15, h = (row >> 11) & 15, q = row & 2047;
  *(ushort4*)(ob + (size_t)(n * S_LEN + q) * EMB + h * HD + d4 * 4) = o;
}

// ---- output projection: C[4096][1024] = O_bf16 @ W_bf16^T + bias ----
// 128x64 tile, grid (32,16) = 512 blocks (2/CU), prefetch dbuf staging.
__global__ __launch_bounds__(256) void proj_kernel(
    const u16* __restrict__ A, const u16* __restrict__ Bt,
    const float* __restrict__ bias, float* __restrict__ C) {
  __shared__ __align__(16) unsigned char al[2][16384];
  __shared__ __align__(16) unsigned char bl[2][8192];
  int bm = blockIdx.x, bn = blockIdx.y;
  int t = threadIdx.x, w = t >> 6, l = t & 63;
  int l16 = l & 15, g = l >> 4;
  f32x4 zero4 = {0.f, 0.f, 0.f, 0.f};
  f32x4 acc[2][4];
#pragma unroll
  for (int mi = 0; mi < 2; ++mi)
#pragma unroll
    for (int nj = 0; nj < 4; ++nj) acc[mi][nj] = zero4;
  int row_s = t >> 3, cc = t & 7;
  int sc = cc ^ (row_s & 7);
  const u16* ga0 = A + (size_t)(bm * 128 + row_s) * EMB + sc * 8;
  const u16* gb0 = Bt + (size_t)(bn * 64 + row_s) * EMB + sc * 8;

  auto stage = [&](int ks, int nb) {
#pragma unroll
    for (int i = 0; i < 4; ++i)
      GLOAD_LDS16(ga0 + (size_t)i * 32 * EMB + ks * 64, al[nb] + (i * 256 + w * 64) * 16);
#pragma unroll
    for (int i = 0; i < 2; ++i)
      GLOAD_LDS16(gb0 + (size_t)i * 32 * EMB + ks * 64, bl[nb] + (i * 256 + w * 64) * 16);
  };

  stage(0, 0);
  __syncthreads();

  for (int ks = 0; ks < 16; ++ks) {
    int cur = ks & 1;
    if (ks + 1 < 16) stage(ks + 1, cur ^ 1);
    __builtin_amdgcn_s_setprio(1);
#pragma unroll
    for (int hh = 0; hh < 2; ++hh) {
      bf16x8 af[2], bfr[4];
#pragma unroll
      for (int mi = 0; mi < 2; ++mi) {
        int row = w * 32 + mi * 16 + l16;
        af[mi] = *(const bf16x8*)(al[cur] + row * 128 + ((hh * 64 + g * 16) ^ ((row & 7) << 4)));
      }
#pragma unroll
      for (int nj = 0; nj < 4; ++nj) {
        int row = nj * 16 + l16;
        bfr[nj] = *(const bf16x8*)(bl[cur] + row * 128 + ((hh * 64 + g * 16) ^ ((row & 7) << 4)));
      }
#pragma unroll
      for (int mi = 0; mi < 2; ++mi)
#pragma unroll
        for (int nj = 0; nj < 4; ++nj) acc[mi][nj] = MFMA16(af[mi], bfr[nj], acc[mi][nj]);
    }
    __builtin_amdgcn_s_setprio(0);
    __syncthreads();
  }
#pragma unroll
  for (int nj = 0; nj < 4; ++nj) {
    int j = bn * 64 + nj * 16 + l16;
    float bj = bias[j];
#pragma unroll
    for (int mi = 0; mi < 2; ++mi) {
      int i0 = bm * 128 + w * 32 + mi * 16 + g * 4;
#pragma unroll
      for (int r = 0; r < 4; ++r) C[(size_t)(i0 + r) * EMB + j] = acc[mi][nj][r] + bj;
    }
  }
}

extern "C" void kernel_launch(void* const* d_in, const int* in_sizes, int n_in,
                              void* d_out, int out_size, void* d_ws, size_t ws_size,
                              hipStream_t stream) {
  const float* values = (const float*)d_in[0];
  const float* keys = (const float*)d_in[1];
  const float* query = (const float*)d_in[2];
  const int* mask = (const int*)d_in[3];
  const float* W = (const float*)d_in[4];
  const float* bias = (const float*)d_in[5];
  float* out = (float*)d_out;

  u16* kb = (u16*)d_ws;                    // 8 MB
  u16* vt = kb + 4194304;                  // 8 MB
  u16* ob = vt + 4194304;                  // 8 MB
  u16* wb = ob + 4194304;                  // 2 MB
  unsigned char* fl2 = (unsigned char*)(wb + 1048576);  // 64 KB reserved
  float* po = (float*)(fl2 + 65536);       // 2 * 65536 * 64 fp32 = 32 MB
  float2* ml = (float2*)(po + 2 * (size_t)NROWS * HD);  // 1 MB

  prep_kernel<<<3328, 256, 0, stream>>>(values, keys, W, mask, vt, kb, wb, fl2);
  attn_kernel<<<1024, 256, 0, stream>>>(query, kb, vt, mask, fl2, po, ml);
  combine_kernel<<<4096, 256, 0, stream>>>(po, ml, ob);
  proj_kernel<<<dim3(32, 16), 256, 0, stream>>>(ob, wb, bias, out);
}

// Round 10
// 87.558 us; speedup vs baseline: 1.0576x; 1.0381x over previous
//
#include <hip/hip_runtime.h>
#include <stdint.h>

// Problem constants (N=2, S=2048, E=1024, H=16, D=64)
#define S_LEN 2048
#define EMB 1024
#define NHEADS 16
#define HD 64
#define LOG2E 1.4426950408889634f
#define NROWS 65536  // N * H * S

typedef __bf16 bf16x8 __attribute__((ext_vector_type(8)));
typedef float f32x4 __attribute__((ext_vector_type(4)));
typedef unsigned short u16;

#define MFMA16(a, b, c) __builtin_amdgcn_mfma_f32_16x16x32_bf16(a, b, c, 0, 0, 0)
#define GLOAD_LDS16(gp, lp)                                        \
  __builtin_amdgcn_global_load_lds(                                \
      (const __attribute__((address_space(1))) unsigned int*)(gp), \
      (__attribute__((address_space(3))) unsigned int*)(lp), 16, 0, 0)

__device__ __forceinline__ u16 bf16r(float x) {
  union { float f; unsigned int u; } c; c.f = x;
  unsigned int u = c.u + 0x7fffu + ((c.u >> 16) & 1u);
  return (u16)(u >> 16);
}

__device__ __forceinline__ unsigned int cvt_pk_bf16(float lo, float hi) {
  unsigned int r;
  asm("v_cvt_pk_bf16_f32 %0, %1, %2" : "=v"(r) : "v"(lo), "v"(hi));
  return r;
}

__device__ __forceinline__ float fexp2(float x) {
  float r;
  asm("v_exp_f32 %0, %1" : "=v"(r) : "v"(x));
  return r;
}

__device__ __forceinline__ float fmax3(float a, float b, float c) {
  float r;
  asm("v_max3_f32 %0, %1, %2, %3" : "=v"(r) : "v"(a), "v"(b), "v"(c));
  return r;
}

__device__ __forceinline__ float bf_lo(unsigned int v) {
  union { unsigned int u; float f; } c; c.u = v << 16; return c.f;
}
__device__ __forceinline__ float bf_hi(unsigned int v) {
  union { unsigned int u; float f; } c; c.u = v & 0xffff0000u; return c.f;
}

// k-axis permutation applied to V columns so the PV A-fragment (P) is formed
// from each lane's own QK^T outputs with zero cross-lane traffic (16x16 MFMA).
__device__ __forceinline__ int kperm(int k) {
  int kb = (k >> 4) & 3, g = (k >> 2) & 3, r = k & 3;
  return (kb >> 1) * 32 + g * 8 + (kb & 1) * 4 + r;
}

// ---- fused preprocessing: V-transpose(+k-perm) | K cvt | W cvt | mask flags ----
__global__ __launch_bounds__(256) void prep_kernel(
    const float* __restrict__ values, const float* __restrict__ keys,
    const float* __restrict__ W, const int* __restrict__ mask,
    u16* __restrict__ vt, u16* __restrict__ kb, u16* __restrict__ wb,
    unsigned char* __restrict__ fl2) {
  __shared__ u16 tile[64][65];
  __shared__ int s_ok[4];
  int b = blockIdx.x;
  int t = threadIdx.x;
  if (b < 1024) {
    // V transpose: v[n][s][h*64+d] fp32 -> vt[n][h][d][kperm(s)] bf16
    int st = b & 31, h = (b >> 5) & 15, n = b >> 9;
    int s0 = st * 64;
    int d = t & 63, r4 = t >> 6;
#pragma unroll
    for (int i = 0; i < 16; ++i) {
      int s = r4 + i * 4;
      float x = values[(size_t)(n * S_LEN + s0 + s) * EMB + h * HD + d];
      tile[s][d] = bf16r(x);
    }
    __syncthreads();
    int sp = s0 + kperm(d);  // permuted column position
#pragma unroll
    for (int i = 0; i < 16; ++i) {
      int dd = r4 + i * 4;
      vt[(size_t)((n * NHEADS + h) * HD + dd) * S_LEN + sp] = tile[d][dd];
    }
  } else if (b < 2048) {
    // K fp32 -> bf16 (1,048,576 float4)
    int idx = (b - 1024) * 256 + t;
    const float4* in4 = (const float4*)keys;
    ushort4* out4 = (ushort4*)kb;
#pragma unroll
    for (int j = 0; j < 4; ++j) {
      float4 v = in4[idx + j * 262144];
      ushort4 o;
      o.x = bf16r(v.x); o.y = bf16r(v.y); o.z = bf16r(v.z); o.w = bf16r(v.w);
      out4[idx + j * 262144] = o;
    }
  } else if (b < 2304) {
    // W fp32 -> bf16 (262,144 float4)
    int idx = (b - 2048) * 256 + t;
    const float4* in4 = (const float4*)W;
    ushort4* out4 = (ushort4*)wb;
#pragma unroll
    for (int j = 0; j < 4; ++j) {
      float4 v = in4[idx + j * 65536];
      ushort4 o;
      o.x = bf16r(v.x); o.y = bf16r(v.y); o.z = bf16r(v.z); o.w = bf16r(v.w);
      out4[idx + j * 65536] = o;
    }
  } else {
    // mask flags: fl2[(n*16+qt)*32+kt] = all(mask block 128q x 64k != 0)
    int idx = b - 2304;
    int kt = idx & 31, qt = (idx >> 5) & 15, n = idx >> 9;
    int qr = t >> 1, c8 = t & 1;
    const int4* mp = (const int4*)(mask + (size_t)n * S_LEN * S_LEN +
                                   (size_t)(qt * 128 + qr) * S_LEN + kt * 64) + c8 * 8;
    int ok = 1;
#pragma unroll
    for (int i = 0; i < 8; ++i) {
      int4 m = mp[i];
      ok &= (m.x != 0) & (m.y != 0) & (m.z != 0) & (m.w != 0);
    }
    ok = __all(ok);
    if ((t & 63) == 0) s_ok[t >> 6] = ok;
    __syncthreads();
    if (t == 0) fl2[idx] = (unsigned char)(s_ok[0] & s_ok[1] & s_ok[2] & s_ok[3]);
  }
}

// ---- flash attention, split-K by 2: each block does 16 of 32 K/V tiles ----
// 4 waves x 32 q (2x16 subtiles) = 128 q/block, grid 1024 (4 blocks/CU).
// Swapped QK^T, log2-domain softmax, defer-max (v_max3 tree), skip-sub fast
// path, row-sum via MFMA(P, ones), in-register P (k-permuted V), unroll-2
// prefetch dbuf staging. Writes unnormalized bf16 partials + (m,l) per row.
__global__ __launch_bounds__(256, 4) void attn_kernel(
    const float* __restrict__ query, const u16* __restrict__ kbuf,
    const u16* __restrict__ vt, const int* __restrict__ mask,
    const unsigned char* __restrict__ fl2, u16* __restrict__ po,
    float2* __restrict__ ml) {
  __shared__ __align__(16) unsigned char kl[2][8192];  // K tile [64 k][64 d] dbuf, swizzled
  __shared__ __align__(16) unsigned char vl[2][8192];  // Vt tile [64 d][64 k'] dbuf, swizzled

  int b = blockIdx.x;
  b = (b & 7) * 128 + (b >> 3);  // XCD swizzle: 4 heads (both halves) per XCD
  int qt = b & 15, half = (b >> 4) & 1, h = (b >> 5) & 15, n = b >> 9;
  int t = threadIdx.x, w = t >> 6, l = t & 63, l16 = l & 15, g = l >> 4;
  int q0 = qt * 128 + w * 32;  // wave q base; subtile u covers q0+u*16 .. +15
  int kt0 = half * 16;

  // Q fragments (B-operand of swapped QK): pre-scale by LOG2E/32 -> log2 domain
  const float QS = 0.03125f * LOG2E;
  bf16x8 aq[2][2];
#pragma unroll
  for (int u = 0; u < 2; ++u)
#pragma unroll
    for (int hh = 0; hh < 2; ++hh) {
      const float* qp = query + (size_t)(n * S_LEN + q0 + u * 16 + l16) * EMB +
                        h * HD + hh * 32 + g * 8;
      float4 f0 = *(const float4*)qp;
      float4 f1 = *(const float4*)(qp + 4);
      union { bf16x8 v; unsigned int u32[4]; } qq;
      qq.u32[0] = cvt_pk_bf16(f0.x * QS, f0.y * QS);
      qq.u32[1] = cvt_pk_bf16(f0.z * QS, f0.w * QS);
      qq.u32[2] = cvt_pk_bf16(f1.x * QS, f1.y * QS);
      qq.u32[3] = cvt_pk_bf16(f1.z * QS, f1.w * QS);
      aq[u][hh] = qq.v;
    }

  // all-ones bf16 B-fragment for the row-sum MFMA
  union { bf16x8 v; unsigned int u32[4]; } one_i;
  one_i.u32[0] = 0x3F803F80u; one_i.u32[1] = 0x3F803F80u;
  one_i.u32[2] = 0x3F803F80u; one_i.u32[3] = 0x3F803F80u;
  bf16x8 ones = one_i.v;

  f32x4 zero4 = {0.f, 0.f, 0.f, 0.f};
  f32x4 acc[2][4];
  float lrun[2] = {0.f, 0.f}, mrun[2] = {0.f, 0.f};
#pragma unroll
  for (int u = 0; u < 2; ++u)
#pragma unroll
    for (int db = 0; db < 4; ++db) acc[u][db] = zero4;

  int row_s = t >> 3, cc = t & 7;  // staging row 0..31, 16B chunk 0..7
  int sc = cc ^ (row_s & 7);       // pre-swizzled source chunk
  const u16* gk0 = kbuf + (size_t)(n * S_LEN + row_s) * EMB + h * HD + sc * 8;
  const u16* gv0 = vt + (size_t)((n * NHEADS + h) * HD + row_s) * S_LEN + sc * 8;

  auto stage = [&](int kt, int nb) {
    const u16* gk = gk0 + (size_t)kt * 64 * EMB;
    const u16* gv = gv0 + kt * 64;
    GLOAD_LDS16(gk, kl[nb] + (w * 64) * 16);
    GLOAD_LDS16(gk + 32 * EMB, kl[nb] + (256 + w * 64) * 16);
    GLOAD_LDS16(gv, vl[nb] + (w * 64) * 16);
    GLOAD_LDS16(gv + 32 * S_LEN, vl[nb] + (256 + w * 64) * 16);
  };

  auto body = [&](int kt, const unsigned char* kc, const unsigned char* vc) {
    // S^T = K Q^T : lane (l16,g) -> S[k=kb*16+g*4+r][q=q0+u*16+l16] (log2 units)
    f32x4 sf[2][4];
    __builtin_amdgcn_s_setprio(1);
#pragma unroll
    for (int kb = 0; kb < 4; ++kb) {
      int row = kb * 16 + l16;
      const unsigned char* kr = kc + row * 128;
      int sw = (row & 7) << 4;
      bf16x8 bk0 = *(const bf16x8*)(kr + ((g * 16) ^ sw));
      bf16x8 bk1 = *(const bf16x8*)(kr + ((64 + g * 16) ^ sw));
#pragma unroll
      for (int u = 0; u < 2; ++u) {
        f32x4 z = zero4;
        z = MFMA16(bk0, aq[u][0], z);
        z = MFMA16(bk1, aq[u][1], z);
        sf[u][kb] = z;
      }
    }
    __builtin_amdgcn_s_setprio(0);

    unsigned char fflag = fl2[((n * 16 + qt) * 32) + kt];
    if (!fflag) {  // rare: per-element mask (log2 domain: -100 ~ zero prob)
#pragma unroll
      for (int u = 0; u < 2; ++u) {
        const int* mrow = mask + (size_t)n * S_LEN * S_LEN +
                          (size_t)(q0 + u * 16 + l16) * S_LEN + kt * 64 + g * 4;
#pragma unroll
        for (int kb = 0; kb < 4; ++kb) {
          int4 mm = *(const int4*)(mrow + kb * 16);
          if (mm.x == 0) sf[u][kb][0] = -100.f;
          if (mm.y == 0) sf[u][kb][1] = -100.f;
          if (mm.z == 0) sf[u][kb][2] = -100.f;
          if (mm.w == 0) sf[u][kb][3] = -100.f;
        }
      }
    }

    bf16x8 pa[2][2];
#pragma unroll
    for (int u = 0; u < 2; ++u) {
      // defer-max: v_max3 tree over this lane's 16 values (its k-slice of row l16)
      float a0 = fmax3(sf[u][0][0], sf[u][0][1], sf[u][0][2]);
      float a1 = fmax3(sf[u][0][3], sf[u][1][0], sf[u][1][1]);
      float a2 = fmax3(sf[u][1][2], sf[u][1][3], sf[u][2][0]);
      float a3 = fmax3(sf[u][2][1], sf[u][2][2], sf[u][2][3]);
      float a4 = fmax3(sf[u][3][0], sf[u][3][1], sf[u][3][2]);
      float lmax = fmaxf(fmax3(a0, a1, a2), fmax3(a3, a4, sf[u][3][3]));
      if (!__all(lmax <= mrun[u] + 8.f)) {  // rare rescale path
        float rmax = fmaxf(lmax, __shfl_xor(lmax, 16));
        rmax = fmaxf(rmax, __shfl_xor(rmax, 32));
        float Mn = fmaxf(mrun[u], rmax);
        float corr = fexp2(mrun[u] - Mn);
        mrun[u] = Mn;
        lrun[u] *= corr;
#pragma unroll
        for (int r = 0; r < 4; ++r) {
          float ca = __shfl(corr, (l & 48) + (g << 2) + r);
#pragma unroll
          for (int db = 0; db < 4; ++db) acc[u][db][r] *= ca;
        }
      }
      // p = 2^(s - m); fast path skips the subtract while mrun == 0 (common)
      float p[4][4];
      if (__all(mrun[u] == 0.f)) {
#pragma unroll
        for (int kb = 0; kb < 4; ++kb)
#pragma unroll
          for (int r = 0; r < 4; ++r) p[kb][r] = fexp2(sf[u][kb][r]);
      } else {
#pragma unroll
        for (int kb = 0; kb < 4; ++kb)
#pragma unroll
          for (int r = 0; r < 4; ++r) p[kb][r] = fexp2(sf[u][kb][r] - mrun[u]);
      }
      // pack A-fragments in-register (k-perm layout)
#pragma unroll
      for (int hh = 0; hh < 2; ++hh) {
        union { bf16x8 v; unsigned int u32[4]; } pp;
        pp.u32[0] = cvt_pk_bf16(p[2 * hh][0], p[2 * hh][1]);
        pp.u32[1] = cvt_pk_bf16(p[2 * hh][2], p[2 * hh][3]);
        pp.u32[2] = cvt_pk_bf16(p[2 * hh + 1][0], p[2 * hh + 1][1]);
        pp.u32[3] = cvt_pk_bf16(p[2 * hh + 1][2], p[2 * hh + 1][3]);
        pa[u][hh] = pp.v;
      }
      // row sum via MFMA(P, ones): z[r] = full-tile rowsum(q-row g*4+r);
      // redistribute so this lane (owner of row l16) gets rowsum(l16).
      f32x4 z = zero4;
      z = MFMA16(pa[u][0], ones, z);
      z = MFMA16(pa[u][1], ones, z);
      float z01 = (l16 & 1) ? z[1] : z[0];
      float z23 = (l16 & 1) ? z[3] : z[2];
      float zsel = (l16 & 2) ? z23 : z01;
      lrun[u] += __shfl(zsel, ((l16 >> 2) << 4) + (l16 & 3));
    }

    // O += P V : A = in-register P, B = permuted Vt rows shared across subtiles
    __builtin_amdgcn_s_setprio(1);
#pragma unroll
    for (int hh = 0; hh < 2; ++hh)
#pragma unroll
      for (int db = 0; db < 4; ++db) {
        int d = db * 16 + l16;
        bf16x8 bv = *(const bf16x8*)(vc + d * 128 + ((hh * 64 + g * 16) ^ ((d & 7) << 4)));
        acc[0][db] = MFMA16(pa[0][hh], bv, acc[0][db]);
        acc[1][db] = MFMA16(pa[1][hh], bv, acc[1][db]);
      }
    __builtin_amdgcn_s_setprio(0);
  };

  stage(kt0, 0);
  __syncthreads();  // first tile staged

  // unroll-2: compile-time LDS buffer pointers -> hoisted ds_read addresses
#pragma unroll 1
  for (int kt = kt0; kt < kt0 + 16; kt += 2) {
    stage(kt + 1, 1);                       // prefetch odd tile into buf1
    body(kt, kl[0], vl[0]);
    __syncthreads();                        // buf1 staged; all done with buf0
    if (kt + 2 < kt0 + 16) stage(kt + 2, 0);  // prefetch next even into buf0
    body(kt + 1, kl[1], vl[1]);
    __syncthreads();                        // buf0 staged; all done with buf1
  }

  // epilogue: lrun holds full row sums; write bf16 partials + (m, l)
  size_t rowbase = (size_t)(n * NHEADS + h) * S_LEN + q0;
#pragma unroll
  for (int u = 0; u < 2; ++u) {
    if (g == 0) {
      float2 v; v.x = mrun[u]; v.y = lrun[u];
      ml[(size_t)half * NROWS + rowbase + u * 16 + l16] = v;
    }
#pragma unroll
    for (int db = 0; db < 4; ++db)
#pragma unroll
      for (int r = 0; r < 4; ++r) {
        size_t rq = rowbase + u * 16 + (g << 2) + r;
        po[((size_t)half * NROWS + rq) * HD + db * 16 + l16] = bf16r(acc[u][db][r]);
      }
  }
}

// ---- combine: merge two bf16 split-K halves with online-softmax algebra ----
// 8 threads/row, 8 d each (bf16x8 = 16B loads, uint4 out).
__global__ __launch_bounds__(256) void combine_kernel(
    const u16* __restrict__ po, const float2* __restrict__ ml,
    u16* __restrict__ ob) {
  int idx = blockIdx.x * 256 + threadIdx.x;  // 0 .. NROWS*8-1
  int row = idx >> 3, d8 = idx & 7;
  float2 a = ml[row], b = ml[NROWS + row];
  float m = fmaxf(a.x, b.x);
  float c0 = fexp2(a.x - m), c1 = fexp2(b.x - m);
  float rinv = 1.f / (a.y * c0 + b.y * c1);
  c0 *= rinv; c1 *= rinv;
  uint4 p0 = *(const uint4*)(po + (size_t)row * HD + d8 * 8);
  uint4 p1 = *(const uint4*)(po + ((size_t)NROWS + row) * HD + d8 * 8);
  uint4 o;
  o.x = cvt_pk_bf16(bf_lo(p0.x) * c0 + bf_lo(p1.x) * c1,
                    bf_hi(p0.x) * c0 + bf_hi(p1.x) * c1);
  o.y = cvt_pk_bf16(bf_lo(p0.y) * c0 + bf_lo(p1.y) * c1,
                    bf_hi(p0.y) * c0 + bf_hi(p1.y) * c1);
  o.z = cvt_pk_bf16(bf_lo(p0.z) * c0 + bf_lo(p1.z) * c1,
                    bf_hi(p0.z) * c0 + bf_hi(p1.z) * c1);
  o.w = cvt_pk_bf16(bf_lo(p0.w) * c0 + bf_lo(p1.w) * c1,
                    bf_hi(p0.w) * c0 + bf_hi(p1.w) * c1);
  int n = row >> 15, h = (row >> 11) & 15, q = row & 2047;
  *(uint4*)(ob + (size_t)(n * S_LEN + q) * EMB + h * HD + d8 * 8) = o;
}

// ---- output projection: C[4096][1024] = O_bf16 @ W_bf16^T + bias ----
// 128x64 tile, grid (32,16) = 512 blocks (3/CU), unroll-2 prefetch dbuf.
__global__ __launch_bounds__(256, 3) void proj_kernel(
    const u16* __restrict__ A, const u16* __restrict__ Bt,
    const float* __restrict__ bias, float* __restrict__ C) {
  __shared__ __align__(16) unsigned char al[2][16384];
  __shared__ __align__(16) unsigned char bl[2][8192];
  int bm = blockIdx.x, bn = blockIdx.y;
  int t = threadIdx.x, w = t >> 6, l = t & 63;
  int l16 = l & 15, g = l >> 4;
  f32x4 zero4 = {0.f, 0.f, 0.f, 0.f};
  f32x4 acc[2][4];
#pragma unroll
  for (int mi = 0; mi < 2; ++mi)
#pragma unroll
    for (int nj = 0; nj < 4; ++nj) acc[mi][nj] = zero4;
  int row_s = t >> 3, cc = t & 7;
  int sc = cc ^ (row_s & 7);
  const u16* ga0 = A + (size_t)(bm * 128 + row_s) * EMB + sc * 8;
  const u16* gb0 = Bt + (size_t)(bn * 64 + row_s) * EMB + sc * 8;

  auto stage = [&](int ks, int nb) {
#pragma unroll
    for (int i = 0; i < 4; ++i)
      GLOAD_LDS16(ga0 + (size_t)i * 32 * EMB + ks * 64, al[nb] + (i * 256 + w * 64) * 16);
#pragma unroll
    for (int i = 0; i < 2; ++i)
      GLOAD_LDS16(gb0 + (size_t)i * 32 * EMB + ks * 64, bl[nb] + (i * 256 + w * 64) * 16);
  };

  auto body = [&](const unsigned char* ac, const unsigned char* bc) {
    __builtin_amdgcn_s_setprio(1);
#pragma unroll
    for (int hh = 0; hh < 2; ++hh) {
      bf16x8 af[2], bfr[4];
#pragma unroll
      for (int mi = 0; mi < 2; ++mi) {
        int row = w * 32 + mi * 16 + l16;
        af[mi] = *(const bf16x8*)(ac + row * 128 + ((hh * 64 + g * 16) ^ ((row & 7) << 4)));
      }
#pragma unroll
      for (int nj = 0; nj < 4; ++nj) {
        int row = nj * 16 + l16;
        bfr[nj] = *(const bf16x8*)(bc + row * 128 + ((hh * 64 + g * 16) ^ ((row & 7) << 4)));
      }
#pragma unroll
      for (int mi = 0; mi < 2; ++mi)
#pragma unroll
        for (int nj = 0; nj < 4; ++nj) acc[mi][nj] = MFMA16(af[mi], bfr[nj], acc[mi][nj]);
    }
    __builtin_amdgcn_s_setprio(0);
  };

  stage(0, 0);
  __syncthreads();

#pragma unroll 1
  for (int ks = 0; ks < 16; ks += 2) {
    stage(ks + 1, 1);
    body(al[0], bl[0]);
    __syncthreads();
    if (ks + 2 < 16) stage(ks + 2, 0);
    body(al[1], bl[1]);
    __syncthreads();
  }
#pragma unroll
  for (int nj = 0; nj < 4; ++nj) {
    int j = bn * 64 + nj * 16 + l16;
    float bj = bias[j];
#pragma unroll
    for (int mi = 0; mi < 2; ++mi) {
      int i0 = bm * 128 + w * 32 + mi * 16 + g * 4;
#pragma unroll
      for (int r = 0; r < 4; ++r) C[(size_t)(i0 + r) * EMB + j] = acc[mi][nj][r] + bj;
    }
  }
}

extern "C" void kernel_launch(void* const* d_in, const int* in_sizes, int n_in,
                              void* d_out, int out_size, void* d_ws, size_t ws_size,
                              hipStream_t stream) {
  const float* values = (const float*)d_in[0];
  const float* keys = (const float*)d_in[1];
  const float* query = (const float*)d_in[2];
  const int* mask = (const int*)d_in[3];
  const float* W = (const float*)d_in[4];
  const float* bias = (const float*)d_in[5];
  float* out = (float*)d_out;

  u16* kb = (u16*)d_ws;                    // 8 MB
  u16* vt = kb + 4194304;                  // 8 MB
  u16* ob = vt + 4194304;                  // 8 MB
  u16* wb = ob + 4194304;                  // 2 MB
  unsigned char* fl2 = (unsigned char*)(wb + 1048576);  // 64 KB reserved
  u16* po = (u16*)(fl2 + 65536);           // 2 * 65536 * 64 bf16 = 16 MB
  float2* ml = (float2*)(po + 2 * (size_t)NROWS * HD);  // 1 MB

  prep_kernel<<<3328, 256, 0, stream>>>(values, keys, W, mask, vt, kb, wb, fl2);
  attn_kernel<<<1024, 256, 0, stream>>>(query, kb, vt, mask, fl2, po, ml);
  combine_kernel<<<2048, 256, 0, stream>>>(po, ml, ob);
  proj_kernel<<<dim3(32, 16), 256, 0, stream>>>(ob, wb, bias, out);
}